// Round 1
// baseline (281.156 us; speedup 1.0000x reference)
//
#include <hip/hip_runtime.h>
#include <hip/hip_bf16.h>

typedef __attribute__((ext_vector_type(8))) __bf16 bf16x8;
typedef __attribute__((ext_vector_type(4))) float f32x4;

constexpr int S_LEN = 4096;
constexpr int H = 8;
constexpr int HKV = 2;
constexpr int D = 64;
constexpr int G = H / HKV;           // 4 query heads per kv head
constexpr int QBLK = 16;             // q rows per wave
constexpr int WAVES = 4;             // waves per block
constexpr int KVBLK = 32;            // keys per tile
constexpr float SM_SCALE = 0.125f;   // 1/sqrt(64)

__device__ __forceinline__ bf16x8 load8_bf16(const float* p) {
  f32x4 a = *reinterpret_cast<const f32x4*>(p);
  f32x4 b = *reinterpret_cast<const f32x4*>(p + 4);
  bf16x8 r;
  r[0] = (__bf16)a[0]; r[1] = (__bf16)a[1]; r[2] = (__bf16)a[2]; r[3] = (__bf16)a[3];
  r[4] = (__bf16)b[0]; r[5] = (__bf16)b[1]; r[6] = (__bf16)b[2]; r[7] = (__bf16)b[3];
  return r;
}

__global__ __launch_bounds__(WAVES * 64) void gqa_fwd_kernel(
    const float* __restrict__ q, const float* __restrict__ k,
    const float* __restrict__ v, float* __restrict__ out) {
  const int lane = threadIdx.x & 63;
  const int wid  = threadIdx.x >> 6;
  const int r    = lane & 15;   // frag row/col index
  const int g4   = lane >> 4;   // frag k-group / C-row group

  const int bid = blockIdx.x;
  const int h   = bid % H;
  const int qb  = (S_LEN / (QBLK * WAVES) - 1) - (bid / H);  // heavy blocks first
  const int hkv = h / G;
  const int q0  = qb * (QBLK * WAVES) + wid * QBLK;

  // per-wave LDS scratch for P (C-layout -> A-layout transpose)
  __shared__ __bf16 plds[WAVES][QBLK][KVBLK];

  // ---- Q fragments (held for whole kernel): A[row=r][kdim = g4*8+i (+32)] ----
  const float* qbase = q + ((size_t)(q0 + r) * H + h) * D + g4 * 8;
  const bf16x8 qf0 = load8_bf16(qbase);
  const bf16x8 qf1 = load8_bf16(qbase + 32);

  float m_r[4], l_r[4];
  f32x4 acc[4];
#pragma unroll
  for (int j = 0; j < 4; ++j) { m_r[j] = -1e30f; l_r[j] = 0.0f; }
#pragma unroll
  for (int dc = 0; dc < 4; ++dc) acc[dc] = f32x4{0.f, 0.f, 0.f, 0.f};

  const int ntiles = (q0 + QBLK + KVBLK - 1) / KVBLK;  // keys 0 .. q0+15 covered
  for (int t = 0; t < ntiles; ++t) {
    const int kb = t * KVBLK;

    // ---- S = Q K^T : two 16-key col-halves, two 32-deep d-steps ----
    f32x4 sf[2];
#pragma unroll
    for (int c = 0; c < 2; ++c) {
      const float* kptr = k + ((size_t)(kb + c * 16 + r) * HKV + hkv) * D + g4 * 8;
      bf16x8 kf0 = load8_bf16(kptr);
      bf16x8 kf1 = load8_bf16(kptr + 32);
      f32x4 z = f32x4{0.f, 0.f, 0.f, 0.f};
      z = __builtin_amdgcn_mfma_f32_16x16x32_bf16(qf0, kf0, z, 0, 0, 0);
      z = __builtin_amdgcn_mfma_f32_16x16x32_bf16(qf1, kf1, z, 0, 0, 0);
      sf[c] = z;
    }

    // ---- V B-fragments for the 4 d-chunks: B[k=g4*8+i][col = dc*16 + r] ----
    bf16x8 vb[4];
#pragma unroll
    for (int i = 0; i < 8; ++i) {
      const float* vrow = v + ((size_t)(kb + g4 * 8 + i) * HKV + hkv) * D + r;
#pragma unroll
      for (int dc = 0; dc < 4; ++dc) vb[dc][i] = (__bf16)vrow[dc * 16];
    }

    // ---- online softmax (rows = q0 + g4*4 + j, cols spread over 16 lanes) ----
    float pcur[2][4];
#pragma unroll
    for (int j = 0; j < 4; ++j) {
      const int qrow = q0 + g4 * 4 + j;
      float s0 = sf[0][j] * SM_SCALE;
      float s1 = sf[1][j] * SM_SCALE;
      if (kb + r      > qrow) s0 = -1e30f;
      if (kb + 16 + r > qrow) s1 = -1e30f;
      float mx = fmaxf(s0, s1);
#pragma unroll
      for (int msk = 8; msk >= 1; msk >>= 1)
        mx = fmaxf(mx, __shfl_xor(mx, msk, 64));
      const float mnew  = fmaxf(m_r[j], mx);
      const float alpha = __expf(m_r[j] - mnew);
      m_r[j] = mnew;
      float p0 = __expf(s0 - mnew);
      float p1 = __expf(s1 - mnew);
      float ps = p0 + p1;
#pragma unroll
      for (int msk = 8; msk >= 1; msk >>= 1)
        ps += __shfl_xor(ps, msk, 64);
      l_r[j] = l_r[j] * alpha + ps;
#pragma unroll
      for (int dc = 0; dc < 4; ++dc) acc[dc][j] *= alpha;
      pcur[0][j] = p0;
      pcur[1][j] = p1;
    }

    // ---- P: C-layout -> LDS -> A-layout (per-wave slice, no barrier needed) ----
#pragma unroll
    for (int c = 0; c < 2; ++c)
#pragma unroll
      for (int j = 0; j < 4; ++j)
        plds[wid][g4 * 4 + j][c * 16 + r] = (__bf16)pcur[c][j];
    const bf16x8 pa = *reinterpret_cast<const bf16x8*>(&plds[wid][r][g4 * 8]);

    // ---- O += P V ----
#pragma unroll
    for (int dc = 0; dc < 4; ++dc)
      acc[dc] = __builtin_amdgcn_mfma_f32_16x16x32_bf16(pa, vb[dc], acc[dc], 0, 0, 0);
  }

  // ---- epilogue: normalize and store ----
#pragma unroll
  for (int j = 0; j < 4; ++j) {
    const float inv = 1.0f / l_r[j];
    float* orow = out + ((size_t)(q0 + g4 * 4 + j) * H + h) * D;
#pragma unroll
    for (int dc = 0; dc < 4; ++dc)
      orow[dc * 16 + r] = acc[dc][j] * inv;
  }
}

extern "C" void kernel_launch(void* const* d_in, const int* in_sizes, int n_in,
                              void* d_out, int out_size, void* d_ws, size_t ws_size,
                              hipStream_t stream) {
  const float* q = (const float*)d_in[0];
  const float* k = (const float*)d_in[1];
  const float* v = (const float*)d_in[2];
  float* out = (float*)d_out;
  dim3 grid(H * (S_LEN / (QBLK * WAVES)));
  dim3 block(WAVES * 64);
  gqa_fwd_kernel<<<grid, block, 0, stream>>>(q, k, v, out);
}

// Round 2
// 163.967 us; speedup vs baseline: 1.7147x; 1.7147x over previous
//
#include <hip/hip_runtime.h>
#include <hip/hip_bf16.h>

typedef __attribute__((ext_vector_type(8))) __bf16 bf16x8;
typedef __attribute__((ext_vector_type(4))) __bf16 bf16x4;
typedef __attribute__((ext_vector_type(4))) float f32x4;

constexpr int S_LEN = 4096;
constexpr int H = 8;
constexpr int HKV = 2;
constexpr int D = 64;
constexpr int G = H / HKV;           // 4 query heads per kv head
constexpr int QBLK = 16;             // q rows per wave
constexpr int WAVES = 4;             // waves per block -> 64 q rows / block
constexpr int BK = 64;               // keys per tile
constexpr float SM_SCALE = 0.125f;   // 1/sqrt(64), exact power of two

// XOR swizzle for [64][64] bf16 tiles (row stride 128B): flip elem bits 3..5
// with row&7 -> 16B-granular, preserves b128/b64 alignment, kills the
// 16-way same-bank pattern of stride-128B column reads.
__device__ __forceinline__ int swz(int row, int col) {
  return (row * 64 + col) ^ ((row & 7) << 3);
}

__device__ __forceinline__ bf16x8 load8_scaled(const float* p, float scale) {
  f32x4 a = *reinterpret_cast<const f32x4*>(p);
  f32x4 b = *reinterpret_cast<const f32x4*>(p + 4);
  bf16x8 r;
  r[0] = (__bf16)(a[0] * scale); r[1] = (__bf16)(a[1] * scale);
  r[2] = (__bf16)(a[2] * scale); r[3] = (__bf16)(a[3] * scale);
  r[4] = (__bf16)(b[0] * scale); r[5] = (__bf16)(b[1] * scale);
  r[6] = (__bf16)(b[2] * scale); r[7] = (__bf16)(b[3] * scale);
  return r;
}

__global__ __launch_bounds__(WAVES * 64) void gqa_fwd_kernel(
    const float* __restrict__ q, const float* __restrict__ k,
    const float* __restrict__ v, float* __restrict__ out) {
  const int tid  = threadIdx.x;
  const int lane = tid & 63;
  const int wid  = tid >> 6;
  const int r    = lane & 15;   // frag row/col index
  const int g4   = lane >> 4;   // frag k-group / C-row group

  const int bid = blockIdx.x;
  const int h   = bid % H;
  const int qb  = (S_LEN / (QBLK * WAVES) - 1) - (bid / H);  // heavy blocks first
  const int hkv = h / G;
  const int q0  = qb * (QBLK * WAVES) + wid * QBLK;
  const int ntiles = qb + 1;    // same for all 4 waves in the block

  // double-buffered K tile [kv][d] and V^T tile [d][kv], both swizzled bf16
  __shared__ __bf16 klds[2][64 * 64];
  __shared__ __bf16 vlds[2][64 * 64];
  __shared__ __bf16 plds[WAVES][16 * 64];  // per-wave P scratch, swizzled

  // ---- Q fragments, pre-scaled by SM_SCALE (exact: *2^-3) ----
  const float* qbase = q + ((size_t)(q0 + r) * H + h) * D + g4 * 8;
  const bf16x8 qf0 = load8_scaled(qbase, SM_SCALE);
  const bf16x8 qf1 = load8_scaled(qbase + 32, SM_SCALE);

  float m_r[4], l_r[4];
  f32x4 acc[4];
#pragma unroll
  for (int j = 0; j < 4; ++j) { m_r[j] = -1e30f; l_r[j] = 0.0f; }
#pragma unroll
  for (int dc = 0; dc < 4; ++dc) acc[dc] = f32x4{0.f, 0.f, 0.f, 0.f};

  // cooperative stage of tile t into buffer buf: K [kv][d], V^T [d][kv]
  auto stage = [&](int buf, int t) {
#pragma unroll
    for (int u = 0; u < 4; ++u) {
      const int si  = u * 256 + tid;     // 1024 f32x4 segments
      const int row = si >> 4;           // kv index 0..63
      const int c0  = (si & 15) * 4;     // d offset 0..60
      const float* gk = k + ((size_t)((size_t)t * BK + row) * HKV + hkv) * D + c0;
      const float* gv = v + ((size_t)((size_t)t * BK + row) * HKV + hkv) * D + c0;
      f32x4 ka = *reinterpret_cast<const f32x4*>(gk);
      f32x4 va = *reinterpret_cast<const f32x4*>(gv);
      bf16x4 kw;
      kw[0] = (__bf16)ka[0]; kw[1] = (__bf16)ka[1];
      kw[2] = (__bf16)ka[2]; kw[3] = (__bf16)ka[3];
      *reinterpret_cast<bf16x4*>(&klds[buf][swz(row, c0)]) = kw;
#pragma unroll
      for (int jj = 0; jj < 4; ++jj)
        vlds[buf][swz(c0 + jj, row)] = (__bf16)va[jj];  // transpose scatter
    }
  };

  stage(0, 0);
  __syncthreads();
  int cur = 0;

  for (int t = 0; t < ntiles; ++t) {
    if (t + 1 < ntiles) stage(cur ^ 1, t + 1);  // prefetch under compute

    const int kb = t * BK;
    const bool last = (t == ntiles - 1);

    // ---- S = Q K^T : four 16-key col groups, two 32-deep d-steps ----
    f32x4 sf[4];
#pragma unroll
    for (int c = 0; c < 4; ++c) {
      bf16x8 kf0 = *reinterpret_cast<const bf16x8*>(&klds[cur][swz(c * 16 + r, g4 * 8)]);
      bf16x8 kf1 = *reinterpret_cast<const bf16x8*>(&klds[cur][swz(c * 16 + r, 32 + g4 * 8)]);
      f32x4 z = f32x4{0.f, 0.f, 0.f, 0.f};
      z = __builtin_amdgcn_mfma_f32_16x16x32_bf16(qf0, kf0, z, 0, 0, 0);
      z = __builtin_amdgcn_mfma_f32_16x16x32_bf16(qf1, kf1, z, 0, 0, 0);
      sf[c] = z;
    }

    // ---- online softmax; rows = q0 + g4*4 + j, 64 keys over 16 lanes x 4 c ----
#pragma unroll
    for (int j = 0; j < 4; ++j) {
      float s[4];
#pragma unroll
      for (int c = 0; c < 4; ++c) s[c] = sf[c][j];
      if (last) {
        const int qrow = q0 + g4 * 4 + j;
#pragma unroll
        for (int c = 0; c < 4; ++c)
          if (kb + c * 16 + r > qrow) s[c] = -1e30f;
      }
      float mx = fmaxf(fmaxf(s[0], s[1]), fmaxf(s[2], s[3]));
#pragma unroll
      for (int msk = 8; msk >= 1; msk >>= 1)
        mx = fmaxf(mx, __shfl_xor(mx, msk, 64));
      const float mnew  = fmaxf(m_r[j], mx);
      const float alpha = __expf(m_r[j] - mnew);
      m_r[j] = mnew;
      float ps = 0.f;
#pragma unroll
      for (int c = 0; c < 4; ++c) { s[c] = __expf(s[c] - mnew); ps += s[c]; }
#pragma unroll
      for (int msk = 8; msk >= 1; msk >>= 1)
        ps += __shfl_xor(ps, msk, 64);
      l_r[j] = l_r[j] * alpha + ps;
#pragma unroll
      for (int dc = 0; dc < 4; ++dc) acc[dc][j] *= alpha;
#pragma unroll
      for (int c = 0; c < 4; ++c)
        plds[wid][swz(g4 * 4 + j, c * 16 + r)] = (__bf16)s[c];
    }

    // ---- O += P V : A = P from plds, B = V from V^T tile ----
#pragma unroll
    for (int ks = 0; ks < 2; ++ks) {
      bf16x8 pa = *reinterpret_cast<const bf16x8*>(&plds[wid][swz(r, ks * 32 + g4 * 8)]);
#pragma unroll
      for (int dc = 0; dc < 4; ++dc) {
        bf16x8 vf = *reinterpret_cast<const bf16x8*>(
            &vlds[cur][swz(dc * 16 + r, ks * 32 + g4 * 8)]);
        acc[dc] = __builtin_amdgcn_mfma_f32_16x16x32_bf16(pa, vf, acc[dc], 0, 0, 0);
      }
    }

    __syncthreads();
    cur ^= 1;
  }

  // ---- epilogue: normalize and store ----
#pragma unroll
  for (int j = 0; j < 4; ++j) {
    const float inv = 1.0f / l_r[j];
    float* orow = out + ((size_t)(q0 + g4 * 4 + j) * H + h) * D;
#pragma unroll
    for (int dc = 0; dc < 4; ++dc)
      orow[dc * 16 + r] = acc[dc][j] * inv;
  }
}

extern "C" void kernel_launch(void* const* d_in, const int* in_sizes, int n_in,
                              void* d_out, int out_size, void* d_ws, size_t ws_size,
                              hipStream_t stream) {
  const float* q = (const float*)d_in[0];
  const float* k = (const float*)d_in[1];
  const float* v = (const float*)d_in[2];
  float* out = (float*)d_out;
  dim3 grid(H * (S_LEN / (QBLK * WAVES)));
  dim3 block(WAVES * 64);
  gqa_fwd_kernel<<<grid, block, 0, stream>>>(q, k, v, out);
}

// Round 3
// 156.864 us; speedup vs baseline: 1.7923x; 1.0453x over previous
//
#include <hip/hip_runtime.h>
#include <hip/hip_bf16.h>

typedef __attribute__((ext_vector_type(8))) __bf16 bf16x8;
typedef __attribute__((ext_vector_type(4))) __bf16 bf16x4;
typedef __attribute__((ext_vector_type(4))) float f32x4;

constexpr int S_LEN = 4096;
constexpr int H = 8;
constexpr int HKV = 2;
constexpr int D = 64;
constexpr int G = H / HKV;            // 4 query heads per kv head
constexpr int QBLK = 16;              // q rows per wave
constexpr int WAVES = 4;              // waves per block -> 64 q rows / block
constexpr int BK = 64;                // keys per tile
constexpr int CHUNK = 1024;           // keys per split-K chunk
constexpr int NT_CHUNK = CHUNK / BK;  // 16 tiles per chunk
constexpr int NSLOT = S_LEN / CHUNK;  // 4 partial slots
constexpr float SM_SCALE = 0.125f;    // 1/sqrt(64), exact power of two

// XOR swizzle for [64][64] bf16 tiles. f(row) = ((row>>2)^row)&7 takes all 8
// values both over consecutive rows (fragment reads, stride 1) AND over rows
// stepped by 4 (V^T transpose scatter / P writes) -> <=2-way conflicts
// everywhere. 16B-granular: preserves b128 read and bf16x4 write alignment.
__device__ __forceinline__ int swz(int row, int col) {
  return (row * 64 + col) ^ ((((row >> 2) ^ row) & 7) << 3);
}

__device__ __forceinline__ bf16x8 load8_scaled(const float* p, float scale) {
  f32x4 a = *reinterpret_cast<const f32x4*>(p);
  f32x4 b = *reinterpret_cast<const f32x4*>(p + 4);
  bf16x8 r;
  r[0] = (__bf16)(a[0] * scale); r[1] = (__bf16)(a[1] * scale);
  r[2] = (__bf16)(a[2] * scale); r[3] = (__bf16)(a[3] * scale);
  r[4] = (__bf16)(b[0] * scale); r[5] = (__bf16)(b[1] * scale);
  r[6] = (__bf16)(b[2] * scale); r[7] = (__bf16)(b[3] * scale);
  return r;
}

// SPLIT=true: grid 2048 = (qb-rank<<5) | (c<<3) | h, writes partial (acc,m,l).
// SPLIT=false: grid 512, full key range, writes out directly (ws fallback).
template <bool SPLIT>
__global__ __launch_bounds__(WAVES * 64) void gqa_fwd_kernel(
    const float* __restrict__ q, const float* __restrict__ k,
    const float* __restrict__ v, float* __restrict__ out,
    float* __restrict__ po, float* __restrict__ ml) {
  const int tid  = threadIdx.x;
  const int lane = tid & 63;
  const int wid  = tid >> 6;
  const int r    = lane & 15;
  const int g4   = lane >> 4;

  const int bid = blockIdx.x;
  int h, qb, c;
  if (SPLIT) {
    h  = bid & 7;
    c  = (bid >> 3) & (NSLOT - 1);
    qb = 63 - (bid >> 5);            // heavy q-blocks first
    if (c > (qb >> 4)) return;       // chunk beyond this q-block's range
  } else {
    h  = bid % H;
    qb = (S_LEN / (QBLK * WAVES) - 1) - bid / H;
    c  = 0;
  }
  const int hkv   = h / G;
  const int q0    = qb * 64 + wid * QBLK;
  const int nt    = SPLIT ? ((c < (qb >> 4)) ? NT_CHUNK : (qb & 15) + 1) : qb + 1;
  const int kb0   = c * CHUNK;
  const int tmask = qb - c * NT_CHUNK;  // chunk-local tile index needing mask

  __shared__ __bf16 klds[2][64 * 64];
  __shared__ __bf16 vlds[2][64 * 64];
  __shared__ __bf16 plds[WAVES][16 * 64];

  // ---- Q fragments, pre-scaled by SM_SCALE (exact: *2^-3) ----
  const float* qbase = q + ((size_t)(q0 + r) * H + h) * D + g4 * 8;
  const bf16x8 qf0 = load8_scaled(qbase, SM_SCALE);
  const bf16x8 qf1 = load8_scaled(qbase + 32, SM_SCALE);

  float m_r[4], l_r[4];
  f32x4 acc[4];
#pragma unroll
  for (int j = 0; j < 4; ++j) { m_r[j] = -1e30f; l_r[j] = 0.0f; }
#pragma unroll
  for (int dc = 0; dc < 4; ++dc) acc[dc] = f32x4{0.f, 0.f, 0.f, 0.f};

  auto stage = [&](int buf, int t) {
#pragma unroll
    for (int u = 0; u < 4; ++u) {
      const int si  = u * 256 + tid;     // 1024 f32x4 segments
      const int row = si >> 4;           // kv index 0..63
      const int c0  = (si & 15) * 4;     // d offset 0..60
      const size_t gr = (size_t)(kb0 + t * BK + row) * HKV + hkv;
      f32x4 ka = *reinterpret_cast<const f32x4*>(k + gr * D + c0);
      f32x4 va = *reinterpret_cast<const f32x4*>(v + gr * D + c0);
      bf16x4 kw;
      kw[0] = (__bf16)ka[0]; kw[1] = (__bf16)ka[1];
      kw[2] = (__bf16)ka[2]; kw[3] = (__bf16)ka[3];
      *reinterpret_cast<bf16x4*>(&klds[buf][swz(row, c0)]) = kw;
#pragma unroll
      for (int jj = 0; jj < 4; ++jj)
        vlds[buf][swz(c0 + jj, row)] = (__bf16)va[jj];  // transpose scatter
    }
  };

  stage(0, 0);
  __syncthreads();
  int cur = 0;

  for (int t = 0; t < nt; ++t) {
    if (t + 1 < nt) stage(cur ^ 1, t + 1);  // prefetch under compute

    // ---- S = Q K^T ----
    f32x4 sf[4];
#pragma unroll
    for (int cg = 0; cg < 4; ++cg) {
      bf16x8 kf0 = *reinterpret_cast<const bf16x8*>(&klds[cur][swz(cg * 16 + r, g4 * 8)]);
      bf16x8 kf1 = *reinterpret_cast<const bf16x8*>(&klds[cur][swz(cg * 16 + r, 32 + g4 * 8)]);
      f32x4 z = f32x4{0.f, 0.f, 0.f, 0.f};
      z = __builtin_amdgcn_mfma_f32_16x16x32_bf16(qf0, kf0, z, 0, 0, 0);
      z = __builtin_amdgcn_mfma_f32_16x16x32_bf16(qf1, kf1, z, 0, 0, 0);
      sf[cg] = z;
    }

    // ---- online softmax ----
    const bool domask = (t == tmask);
#pragma unroll
    for (int j = 0; j < 4; ++j) {
      float s[4];
#pragma unroll
      for (int cg = 0; cg < 4; ++cg) s[cg] = sf[cg][j];
      if (domask) {
        const int qrow = q0 + g4 * 4 + j;
        const int kb   = kb0 + t * BK;
#pragma unroll
        for (int cg = 0; cg < 4; ++cg)
          if (kb + cg * 16 + r > qrow) s[cg] = -1e30f;
      }
      float mx = fmaxf(fmaxf(s[0], s[1]), fmaxf(s[2], s[3]));
#pragma unroll
      for (int msk = 8; msk >= 1; msk >>= 1)
        mx = fmaxf(mx, __shfl_xor(mx, msk, 64));
      const float mnew  = fmaxf(m_r[j], mx);
      const float alpha = __expf(m_r[j] - mnew);
      m_r[j] = mnew;
      float ps = 0.f;
#pragma unroll
      for (int cg = 0; cg < 4; ++cg) { s[cg] = __expf(s[cg] - mnew); ps += s[cg]; }
#pragma unroll
      for (int msk = 8; msk >= 1; msk >>= 1)
        ps += __shfl_xor(ps, msk, 64);
      l_r[j] = l_r[j] * alpha + ps;
#pragma unroll
      for (int dc = 0; dc < 4; ++dc) acc[dc][j] *= alpha;
#pragma unroll
      for (int cg = 0; cg < 4; ++cg)
        plds[wid][swz(g4 * 4 + j, cg * 16 + r)] = (__bf16)s[cg];
    }

    // ---- O += P V ----
#pragma unroll
    for (int ks = 0; ks < 2; ++ks) {
      bf16x8 pa = *reinterpret_cast<const bf16x8*>(&plds[wid][swz(r, ks * 32 + g4 * 8)]);
#pragma unroll
      for (int dc = 0; dc < 4; ++dc) {
        bf16x8 vf = *reinterpret_cast<const bf16x8*>(
            &vlds[cur][swz(dc * 16 + r, ks * 32 + g4 * 8)]);
        acc[dc] = __builtin_amdgcn_mfma_f32_16x16x32_bf16(pa, vf, acc[dc], 0, 0, 0);
      }
    }

    __syncthreads();
    cur ^= 1;
  }

  // ---- epilogue ----
#pragma unroll
  for (int j = 0; j < 4; ++j) {
    const int qrow = q0 + g4 * 4 + j;
    if (SPLIT) {
      float* prow = po + ((size_t)(c * S_LEN + qrow) * H + h) * D;
#pragma unroll
      for (int dc = 0; dc < 4; ++dc) prow[dc * 16 + r] = acc[dc][j];
      if (r == 0) {
        float* m2 = ml + ((size_t)(c * S_LEN + qrow) * H + h) * 2;
        m2[0] = m_r[j];
        m2[1] = l_r[j];
      }
    } else {
      const float inv = 1.0f / l_r[j];
      float* orow = out + ((size_t)qrow * H + h) * D;
#pragma unroll
      for (int dc = 0; dc < 4; ++dc) orow[dc * 16 + r] = acc[dc][j] * inv;
    }
  }
}

// one wave per (row, head): merge <=4 chunk partials, normalize, store.
__global__ __launch_bounds__(256) void combine_kernel(
    const float* __restrict__ po, const float* __restrict__ ml,
    float* __restrict__ out) {
  const int lane = threadIdx.x & 63;
  const int widx = (blockIdx.x << 2) + (threadIdx.x >> 6);  // 0..32767
  const int h    = widx & 7;
  const int row  = widx >> 3;
  const int cmax = row >> 10;  // row / CHUNK

  float mv[NSLOT];
  float M = -1e30f;
#pragma unroll
  for (int cc = 0; cc < NSLOT; ++cc) {
    mv[cc] = (cc <= cmax) ? ml[((size_t)(cc * S_LEN + row) * H + h) * 2] : -1e30f;
    M = fmaxf(M, mv[cc]);
  }
  float lsum = 0.f, osum = 0.f;
#pragma unroll
  for (int cc = 0; cc < NSLOT; ++cc) {
    if (cc <= cmax) {
      const float w = __expf(mv[cc] - M);
      lsum += w * ml[((size_t)(cc * S_LEN + row) * H + h) * 2 + 1];
      osum += w * po[((size_t)(cc * S_LEN + row) * H + h) * D + lane];
    }
  }
  out[((size_t)row * H + h) * D + lane] = osum / lsum;
}

extern "C" void kernel_launch(void* const* d_in, const int* in_sizes, int n_in,
                              void* d_out, int out_size, void* d_ws, size_t ws_size,
                              hipStream_t stream) {
  const float* q = (const float*)d_in[0];
  const float* k = (const float*)d_in[1];
  const float* v = (const float*)d_in[2];
  float* out = (float*)d_out;

  const size_t po_elems = (size_t)NSLOT * S_LEN * H * D;
  const size_t ml_elems = (size_t)NSLOT * S_LEN * H * 2;
  const size_t need = (po_elems + ml_elems) * sizeof(float);

  if (ws_size >= need) {
    float* po = (float*)d_ws;
    float* ml = po + po_elems;
    gqa_fwd_kernel<true><<<dim3(8 * 64 * NSLOT), dim3(WAVES * 64), 0, stream>>>(
        q, k, v, out, po, ml);
    combine_kernel<<<dim3(S_LEN * H / 4), dim3(256), 0, stream>>>(po, ml, out);
  } else {
    gqa_fwd_kernel<false><<<dim3(H * (S_LEN / (QBLK * WAVES))), dim3(WAVES * 64), 0, stream>>>(
        q, k, v, out, nullptr, nullptr);
  }
}

// Round 4
// 83.478 us; speedup vs baseline: 3.3680x; 1.8791x over previous
//
#include <hip/hip_runtime.h>
#include <hip/hip_bf16.h>

typedef __attribute__((ext_vector_type(8))) __bf16 bf16x8;
typedef __attribute__((ext_vector_type(4))) __bf16 bf16x4;
typedef __attribute__((ext_vector_type(4))) float f32x4;

constexpr int S_LEN = 4096;
constexpr int H = 8;
constexpr int HKV = 2;
constexpr int D = 64;
constexpr int G = H / HKV;            // 4 query heads per kv head
constexpr int QBLK = 16;              // q rows per wave
constexpr int WAVES = 4;              // waves per block -> 64 q rows / block
constexpr int BK = 64;                // keys per tile
constexpr int CHUNK = 1024;           // keys per split-K chunk
constexpr int NT_CHUNK = CHUNK / BK;  // 16 tiles per chunk
constexpr int NSLOT = S_LEN / CHUNK;  // 4 partial slots
constexpr float SM_SCALE = 0.125f;    // 1/sqrt(64), exact power of two
constexpr float RTHR = 8.0f;          // defer-max threshold (T13)

// XOR swizzle for [64][64] bf16 tiles; f(row)=((row>>2)^row)&7 spreads both
// stride-1 and stride-4 row patterns across 8 bank-groups. 16B-granular.
__device__ __forceinline__ int swz(int row, int col) {
  return (row * 64 + col) ^ ((((row >> 2) ^ row) & 7) << 3);
}

__device__ __forceinline__ bf16x8 load8_scaled(const float* p, float scale) {
  f32x4 a = *reinterpret_cast<const f32x4*>(p);
  f32x4 b = *reinterpret_cast<const f32x4*>(p + 4);
  bf16x8 r;
  r[0] = (__bf16)(a[0] * scale); r[1] = (__bf16)(a[1] * scale);
  r[2] = (__bf16)(a[2] * scale); r[3] = (__bf16)(a[3] * scale);
  r[4] = (__bf16)(b[0] * scale); r[5] = (__bf16)(b[1] * scale);
  r[6] = (__bf16)(b[2] * scale); r[7] = (__bf16)(b[3] * scale);
  return r;
}

// Swapped-operand flash attention: S^T = mfma(K,Q) so each lane owns one
// q-row (q = lane&15); softmax is in-lane + 2 shuffles. O^T = mfma(V^T,P^T)
// keeps alpha/l per-lane and the output store vectorized.
template <bool SPLIT>
__global__ __launch_bounds__(256, 4) void gqa_fwd_kernel(
    const float* __restrict__ q, const float* __restrict__ k,
    const float* __restrict__ v, float* __restrict__ out,
    float* __restrict__ po, float* __restrict__ ml) {
  const int tid  = threadIdx.x;
  const int lane = tid & 63;
  const int wid  = tid >> 6;
  const int r    = lane & 15;   // q-row within wave tile; also frag row index
  const int g4   = lane >> 4;

  const int bid = blockIdx.x;
  int h, qb, c;
  if (SPLIT) {
    h  = bid & 7;
    c  = (bid >> 3) & (NSLOT - 1);
    qb = 63 - (bid >> 5);            // heavy q-blocks first
    if (c > (qb >> 4)) return;       // chunk beyond this q-block's range
  } else {
    h  = bid % H;
    qb = 63 - bid / H;
    c  = 0;
  }
  const int hkv   = h / G;
  const int q0    = qb * 64 + wid * QBLK;
  const int nt    = SPLIT ? ((c < (qb >> 4)) ? NT_CHUNK : (qb & 15) + 1) : qb + 1;
  const int kb0   = c * CHUNK;
  const int tmask = qb - c * NT_CHUNK;  // chunk-local tile index needing mask

  __shared__ __bf16 klds[2][64 * 64];
  __shared__ __bf16 vlds[2][64 * 64];   // stored transposed: [d][kv]
  __shared__ __bf16 plds[WAVES][16 * 64];  // P^T scratch as [q][key]

  // ---- Q B-fragment, pre-scaled (exact *2^-3): lane holds Q[q0+r][g4*8+i] ----
  const float* qbase = q + ((size_t)(q0 + r) * H + h) * D + g4 * 8;
  const bf16x8 qf0 = load8_scaled(qbase, SM_SCALE);
  const bf16x8 qf1 = load8_scaled(qbase + 32, SM_SCALE);

  float m_r = -1e30f, l_r = 0.0f;
  f32x4 acc[4];
#pragma unroll
  for (int dc = 0; dc < 4; ++dc) acc[dc] = f32x4{0.f, 0.f, 0.f, 0.f};

  // ---- async-split staging (T14): load -> regs early, LDS write late ----
  const int srow = tid >> 4;        // 0..15
  const int sc0  = (tid & 15) * 4;  // 0..60
  f32x4 lk[4], lv[4];
  auto stage_load = [&](int t) {
#pragma unroll
    for (int u = 0; u < 4; ++u) {
      const size_t gr = ((size_t)(kb0 + t * BK + u * 16 + srow) * HKV + hkv) * D + sc0;
      lk[u] = *reinterpret_cast<const f32x4*>(k + gr);
      lv[u] = *reinterpret_cast<const f32x4*>(v + gr);
    }
  };
  auto stage_write = [&](int buf) {
#pragma unroll
    for (int u = 0; u < 4; ++u) {
      const int row = u * 16 + srow;
      bf16x4 kw;
      kw[0] = (__bf16)lk[u][0]; kw[1] = (__bf16)lk[u][1];
      kw[2] = (__bf16)lk[u][2]; kw[3] = (__bf16)lk[u][3];
      *reinterpret_cast<bf16x4*>(&klds[buf][swz(row, sc0)]) = kw;
#pragma unroll
      for (int jj = 0; jj < 4; ++jj)
        vlds[buf][swz(sc0 + jj, row)] = (__bf16)lv[u][jj];  // transpose scatter
    }
  };

  stage_load(0);
  stage_write(0);
  if (nt > 1) stage_load(1);
  __syncthreads();
  int cur = 0;

  for (int t = 0; t < nt; ++t) {
    // ---- S^T = K Q : lane gets score[key=kb+cg*16+g4*4+j][q=q0+r] ----
    f32x4 sf[4];
    __builtin_amdgcn_s_setprio(1);
#pragma unroll
    for (int cg = 0; cg < 4; ++cg) {
      bf16x8 kf0 = *reinterpret_cast<const bf16x8*>(&klds[cur][swz(cg * 16 + r, g4 * 8)]);
      bf16x8 kf1 = *reinterpret_cast<const bf16x8*>(&klds[cur][swz(cg * 16 + r, 32 + g4 * 8)]);
      f32x4 z = f32x4{0.f, 0.f, 0.f, 0.f};
      z = __builtin_amdgcn_mfma_f32_16x16x32_bf16(kf0, qf0, z, 0, 0, 0);
      z = __builtin_amdgcn_mfma_f32_16x16x32_bf16(kf1, qf1, z, 0, 0, 0);
      sf[cg] = z;
    }
    __builtin_amdgcn_s_setprio(0);

    if (t == tmask) {  // causal mask, last tile of this block's range only
      const int kb = kb0 + t * BK;
#pragma unroll
      for (int cg = 0; cg < 4; ++cg)
#pragma unroll
        for (int j = 0; j < 4; ++j)
          if (kb + cg * 16 + g4 * 4 + j > q0 + r) sf[cg][j] = -1e30f;
    }

    // ---- row max: in-lane tree over 16 values + 2 shuffles ----
    float mx = -1e30f;
#pragma unroll
    for (int cg = 0; cg < 4; ++cg)
      mx = fmaxf(mx, fmaxf(fmaxf(sf[cg][0], sf[cg][1]), fmaxf(sf[cg][2], sf[cg][3])));
    mx = fmaxf(mx, __shfl_xor(mx, 16, 64));
    mx = fmaxf(mx, __shfl_xor(mx, 32, 64));

    // ---- defer-max (T13): only rescale when the max moved a lot ----
    if (!__all(mx - m_r <= RTHR)) {
      const float mnew  = fmaxf(m_r, mx);
      const float alpha = __expf(m_r - mnew);
      l_r *= alpha;
#pragma unroll
      for (int dc = 0; dc < 4; ++dc) acc[dc] *= alpha;
      m_r = mnew;
    }

    // ---- P = exp(S - m), all independent; write P^T rows to LDS ----
    float ps = 0.f;
#pragma unroll
    for (int cg = 0; cg < 4; ++cg) {
      bf16x4 pw;
#pragma unroll
      for (int j = 0; j < 4; ++j) {
        const float p = __expf(sf[cg][j] - m_r);
        ps += p;
        pw[j] = (__bf16)p;
      }
      *reinterpret_cast<bf16x4*>(&plds[wid][swz(r, cg * 16 + g4 * 4)]) = pw;
    }
    ps += __shfl_xor(ps, 16, 64);
    ps += __shfl_xor(ps, 32, 64);
    l_r += ps;

    // ---- O^T += V^T P^T : acc[dc] holds O[q=q0+r][d=dc*16+g4*4+j] ----
    __builtin_amdgcn_s_setprio(1);
#pragma unroll
    for (int ks = 0; ks < 2; ++ks) {
      bf16x8 pf = *reinterpret_cast<const bf16x8*>(&plds[wid][swz(r, ks * 32 + g4 * 8)]);
#pragma unroll
      for (int dc = 0; dc < 4; ++dc) {
        bf16x8 vf = *reinterpret_cast<const bf16x8*>(
            &vlds[cur][swz(dc * 16 + r, ks * 32 + g4 * 8)]);
        acc[dc] = __builtin_amdgcn_mfma_f32_16x16x32_bf16(vf, pf, acc[dc], 0, 0, 0);
      }
    }
    __builtin_amdgcn_s_setprio(0);

    if (t + 1 < nt) stage_write(cur ^ 1);  // waits vmcnt for loads issued last iter
    if (t + 2 < nt) stage_load(t + 2);     // issue next loads; land during next tile
    __syncthreads();
    cur ^= 1;
  }

  // ---- epilogue: everything for q-row q0+r is lane-local ----
  if (SPLIT) {
    float* prow = po + ((size_t)(c * S_LEN + q0 + r) * H + h) * D;
#pragma unroll
    for (int dc = 0; dc < 4; ++dc)
      *reinterpret_cast<f32x4*>(prow + dc * 16 + g4 * 4) = acc[dc];
    if (g4 == 0) {
      float* m2 = ml + ((size_t)(c * S_LEN + q0 + r) * H + h) * 2;
      m2[0] = m_r;
      m2[1] = l_r;
    }
  } else {
    const float inv = 1.0f / l_r;
    float* orow = out + ((size_t)(q0 + r) * H + h) * D;
#pragma unroll
    for (int dc = 0; dc < 4; ++dc) {
      f32x4 o;
      o[0] = acc[dc][0] * inv; o[1] = acc[dc][1] * inv;
      o[2] = acc[dc][2] * inv; o[3] = acc[dc][3] * inv;
      *reinterpret_cast<f32x4*>(orow + dc * 16 + g4 * 4) = o;
    }
  }
}

// one wave per (row, head): merge <=4 chunk partials, normalize, store.
__global__ __launch_bounds__(256) void combine_kernel(
    const float* __restrict__ po, const float* __restrict__ ml,
    float* __restrict__ out) {
  const int lane = threadIdx.x & 63;
  const int widx = (blockIdx.x << 2) + (threadIdx.x >> 6);  // 0..32767
  const int h    = widx & 7;
  const int row  = widx >> 3;
  const int cmax = row >> 10;  // row / CHUNK

  float mv[NSLOT];
  float M = -1e30f;
#pragma unroll
  for (int cc = 0; cc < NSLOT; ++cc) {
    mv[cc] = (cc <= cmax) ? ml[((size_t)(cc * S_LEN + row) * H + h) * 2] : -1e30f;
    M = fmaxf(M, mv[cc]);
  }
  float lsum = 0.f, osum = 0.f;
#pragma unroll
  for (int cc = 0; cc < NSLOT; ++cc) {
    if (cc <= cmax) {
      const float w = __expf(mv[cc] - M);
      lsum += w * ml[((size_t)(cc * S_LEN + row) * H + h) * 2 + 1];
      osum += w * po[((size_t)(cc * S_LEN + row) * H + h) * D + lane];
    }
  }
  out[((size_t)row * H + h) * D + lane] = osum / lsum;
}

extern "C" void kernel_launch(void* const* d_in, const int* in_sizes, int n_in,
                              void* d_out, int out_size, void* d_ws, size_t ws_size,
                              hipStream_t stream) {
  const float* q = (const float*)d_in[0];
  const float* k = (const float*)d_in[1];
  const float* v = (const float*)d_in[2];
  float* out = (float*)d_out;

  const size_t po_elems = (size_t)NSLOT * S_LEN * H * D;
  const size_t ml_elems = (size_t)NSLOT * S_LEN * H * 2;
  const size_t need = (po_elems + ml_elems) * sizeof(float);

  if (ws_size >= need) {
    float* po = (float*)d_ws;
    float* ml = po + po_elems;
    gqa_fwd_kernel<true><<<dim3(8 * 64 * NSLOT), dim3(WAVES * 64), 0, stream>>>(
        q, k, v, out, po, ml);
    combine_kernel<<<dim3(S_LEN * H / 4), dim3(256), 0, stream>>>(po, ml, out);
  } else {
    gqa_fwd_kernel<false><<<dim3(H * (S_LEN / (QBLK * WAVES))), dim3(WAVES * 64), 0, stream>>>(
        q, k, v, out, nullptr, nullptr);
  }
}

// Round 5
// 82.628 us; speedup vs baseline: 3.4027x; 1.0103x over previous
//
#include <hip/hip_runtime.h>
#include <hip/hip_bf16.h>

typedef __attribute__((ext_vector_type(8))) __bf16 bf16x8;
typedef __attribute__((ext_vector_type(4))) __bf16 bf16x4;
typedef __attribute__((ext_vector_type(4))) float f32x4;

constexpr int S_LEN = 4096;
constexpr int H = 8;
constexpr int HKV = 2;
constexpr int D = 64;
constexpr int BK = 64;               // keys per tile
constexpr int QW = 32;               // q rows per wave (2 halves of 16)
constexpr int WAVES = 4;             // 128 q rows per block
constexpr int QB_ROWS = QW * WAVES;  // 128
constexpr int NQB = S_LEN / QB_ROWS; // 32
// exp2-domain: scores scaled by 1/sqrt(64) * log2(e)
constexpr float QSCALE = 0.125f * 1.44269504088896f;
constexpr float RTHR = 8.0f;         // defer-max threshold (log2 units)

// XOR swizzle for [64][64] bf16 tiles; f(row)=((row>>2)^row)&7 spreads both
// stride-1 and stride-4 row patterns across 8 16B slots. Preserves 16B chunks.
__device__ __forceinline__ int swz(int row, int col) {
  return (row * 64 + col) ^ ((((row >> 2) ^ row) & 7) << 3);
}

__device__ __forceinline__ bf16x8 load8_scaled(const float* p, float scale) {
  f32x4 a = *reinterpret_cast<const f32x4*>(p);
  f32x4 b = *reinterpret_cast<const f32x4*>(p + 4);
  bf16x8 r;
  r[0] = (__bf16)(a[0] * scale); r[1] = (__bf16)(a[1] * scale);
  r[2] = (__bf16)(a[2] * scale); r[3] = (__bf16)(a[3] * scale);
  r[4] = (__bf16)(b[0] * scale); r[5] = (__bf16)(b[1] * scale);
  r[6] = (__bf16)(b[2] * scale); r[7] = (__bf16)(b[3] * scale);
  return r;
}

// CHUNK = 1<<LOG2C keys per split chunk; NSLOT = S/CHUNK partial slots.
// SPLIT=false (with LOG2C=12, NSLOT=1) writes out directly.
template <int LOG2C, bool SPLIT>
__global__ __launch_bounds__(256, 3) void gqa_fwd_kernel(
    const float* __restrict__ q, const float* __restrict__ k,
    const float* __restrict__ v, float* __restrict__ out,
    float* __restrict__ po, float* __restrict__ ml) {
  constexpr int NSLOT = S_LEN >> LOG2C;
  constexpr int LOG2NS = 12 - LOG2C;
  constexpr int TPC = (1 << LOG2C) / BK;  // tiles per full chunk

  const int tid  = threadIdx.x;
  const int lane = tid & 63;
  const int wid  = tid >> 6;
  const int r    = lane & 15;
  const int g4   = lane >> 4;

  const int bid = blockIdx.x;
  const int h   = bid & 7;
  const int c   = (bid >> 3) & (NSLOT - 1);
  const int qb  = (NQB - 1) - (bid >> (3 + LOG2NS));  // heavy q-blocks first
  const int cmax = (qb * QB_ROWS + QB_ROWS - 1) >> LOG2C;
  if (c > cmax) return;
  const int hkv = h >> 2;
  const int q0w = qb * QB_ROWS + wid * QW;            // wave's first q row
  const int nt  = (c < cmax) ? TPC : (2 * (qb + 1) - TPC * cmax);
  const int kb0 = c << LOG2C;

  __shared__ __bf16 klds[2][64 * 64];          // K tile [kv][d], swizzled
  __shared__ __bf16 vlds[2][64 * 64];          // V^T tile [d][kv], swizzled
  __shared__ __bf16 plds[WAVES][QW * 64];      // P^T per wave [q][key]

  // ---- Q B-fragments (held), pre-scaled into exp2 domain ----
  bf16x8 qf[2][2];
#pragma unroll
  for (int h2 = 0; h2 < 2; ++h2)
#pragma unroll
    for (int ks = 0; ks < 2; ++ks)
      qf[h2][ks] = load8_scaled(
          q + ((size_t)(q0w + h2 * 16 + r) * H + h) * D + ks * 32 + g4 * 8, QSCALE);

  float m_[2] = {-1e30f, -1e30f};
  float l_[2] = {0.f, 0.f};            // lane-partial; reduced in epilogue
  f32x4 acc[2][4];
#pragma unroll
  for (int h2 = 0; h2 < 2; ++h2)
#pragma unroll
    for (int dc = 0; dc < 4; ++dc) acc[h2][dc] = f32x4{0.f, 0.f, 0.f, 0.f};

  // ---- staging: coalesced loads (256B / 16-lane group), reg-transposed V ----
  const int s16 = tid >> 4;        // constant within each 16-lane group
  const int s4  = (tid & 15) * 4;
  f32x4 lk[4], lv[4];
  auto stage_load = [&](int t) {
    const int kb = kb0 + t * BK;
#pragma unroll
    for (int u = 0; u < 4; ++u) {
      lk[u] = *reinterpret_cast<const f32x4*>(
          k + ((size_t)(kb + u * 16 + s16) * HKV + hkv) * D + s4);
      lv[u] = *reinterpret_cast<const f32x4*>(
          v + ((size_t)(kb + s16 * 4 + u) * HKV + hkv) * D + s4);
    }
  };
  auto stage_write = [&](int buf) {
#pragma unroll
    for (int u = 0; u < 4; ++u) {
      bf16x4 kw;
      kw[0] = (__bf16)lk[u][0]; kw[1] = (__bf16)lk[u][1];
      kw[2] = (__bf16)lk[u][2]; kw[3] = (__bf16)lk[u][3];
      *reinterpret_cast<bf16x4*>(&klds[buf][swz(u * 16 + s16, s4)]) = kw;
    }
#pragma unroll
    for (int j = 0; j < 4; ++j) {    // 4x4 in-register transpose of V
      bf16x4 vw;
      vw[0] = (__bf16)lv[0][j]; vw[1] = (__bf16)lv[1][j];
      vw[2] = (__bf16)lv[2][j]; vw[3] = (__bf16)lv[3][j];
      *reinterpret_cast<bf16x4*>(&vlds[buf][swz(s4 + j, s16 * 4)]) = vw;
    }
  };

  stage_load(0);
  stage_write(0);
  if (nt > 1) stage_load(1);
  __syncthreads();
  int cur = 0;

  for (int t = 0; t < nt; ++t) {
    const int kb = kb0 + t * BK;
    const bool act1 = (kb <= q0w + 31);   // any row of wave unmasked
    const bool act0 = (kb <= q0w + 15);   // low half unmasked
    if (act1) {
      // ---- S^T = K Q : lane owns score[key=kb+cg*16+g4*4+j][q] ----
      f32x4 sf[2][4];
      __builtin_amdgcn_s_setprio(1);
#pragma unroll
      for (int cg = 0; cg < 4; ++cg) {
        bf16x8 kf0 = *reinterpret_cast<const bf16x8*>(&klds[cur][swz(cg * 16 + r, g4 * 8)]);
        bf16x8 kf1 = *reinterpret_cast<const bf16x8*>(&klds[cur][swz(cg * 16 + r, 32 + g4 * 8)]);
#pragma unroll
        for (int h2 = 0; h2 < 2; ++h2) {
          f32x4 z = f32x4{0.f, 0.f, 0.f, 0.f};
          z = __builtin_amdgcn_mfma_f32_16x16x32_bf16(kf0, qf[h2][0], z, 0, 0, 0);
          z = __builtin_amdgcn_mfma_f32_16x16x32_bf16(kf1, qf[h2][1], z, 0, 0, 0);
          sf[h2][cg] = z;
        }
      }
      __builtin_amdgcn_s_setprio(0);

      // ---- per-half softmax: lane-local, shuffles only on rare rescale ----
#pragma unroll
      for (int h2 = 0; h2 < 2; ++h2) {
        const int qmin = q0w + h2 * 16;
        if (kb > qmin + 15) continue;        // wave-uniform: half fully masked
        if (kb + 63 > qmin) {                // causal mask needed
#pragma unroll
          for (int cg = 0; cg < 4; ++cg)
#pragma unroll
            for (int j = 0; j < 4; ++j)
              if (kb + cg * 16 + g4 * 4 + j > qmin + r) sf[h2][cg][j] = -1e30f;
        }
        float mxl = -1e30f;
#pragma unroll
        for (int cg = 0; cg < 4; ++cg)
          mxl = fmaxf(mxl, fmaxf(fmaxf(sf[h2][cg][0], sf[h2][cg][1]),
                                 fmaxf(sf[h2][cg][2], sf[h2][cg][3])));
        if (!__all(mxl - m_[h2] <= RTHR)) {  // T13 defer-max
          float mx = fmaxf(mxl, __shfl_xor(mxl, 16, 64));
          mx = fmaxf(mx, __shfl_xor(mx, 32, 64));
          const float mnew  = fmaxf(m_[h2], mx);
          const float alpha = exp2f(m_[h2] - mnew);
          l_[h2] *= alpha;
#pragma unroll
          for (int dc = 0; dc < 4; ++dc) acc[h2][dc] *= alpha;
          m_[h2] = mnew;
        }
        float ps = 0.f;
#pragma unroll
        for (int cg = 0; cg < 4; ++cg) {
          bf16x4 pw;
#pragma unroll
          for (int j = 0; j < 4; ++j) {
            const float p = exp2f(sf[h2][cg][j] - m_[h2]);
            ps += p;
            pw[j] = (__bf16)p;
          }
          *reinterpret_cast<bf16x4*>(&plds[wid][swz(h2 * 16 + r, cg * 16 + g4 * 4)]) = pw;
        }
        l_[h2] += ps;
      }

      // ---- O^T += V^T P^T ----
      __builtin_amdgcn_s_setprio(1);
#pragma unroll
      for (int ks = 0; ks < 2; ++ks) {
        bf16x8 pf1 = *reinterpret_cast<const bf16x8*>(&plds[wid][swz(16 + r, ks * 32 + g4 * 8)]);
        bf16x8 pf0;
        if (act0)
          pf0 = *reinterpret_cast<const bf16x8*>(&plds[wid][swz(r, ks * 32 + g4 * 8)]);
#pragma unroll
        for (int dc = 0; dc < 4; ++dc) {
          bf16x8 vf = *reinterpret_cast<const bf16x8*>(
              &vlds[cur][swz(dc * 16 + r, ks * 32 + g4 * 8)]);
          if (act0)
            acc[0][dc] = __builtin_amdgcn_mfma_f32_16x16x32_bf16(vf, pf0, acc[0][dc], 0, 0, 0);
          acc[1][dc] = __builtin_amdgcn_mfma_f32_16x16x32_bf16(vf, pf1, acc[1][dc], 0, 0, 0);
        }
      }
      __builtin_amdgcn_s_setprio(0);
    }

    if (t + 1 < nt) stage_write(cur ^ 1);  // regs from loads issued last iter
    if (t + 2 < nt) stage_load(t + 2);     // land during next tile's compute
    __syncthreads();
    cur ^= 1;
  }

  // ---- epilogue: reduce l once; everything else lane-local ----
#pragma unroll
  for (int h2 = 0; h2 < 2; ++h2) {
    float lsum = l_[h2];
    lsum += __shfl_xor(lsum, 16, 64);
    lsum += __shfl_xor(lsum, 32, 64);
    const int qrow = q0w + h2 * 16 + r;
    if (SPLIT) {
      float* prow = po + ((size_t)(c * S_LEN + qrow) * H + h) * D;
#pragma unroll
      for (int dc = 0; dc < 4; ++dc)
        *reinterpret_cast<f32x4*>(prow + dc * 16 + g4 * 4) = acc[h2][dc];
      if (g4 == 0) {
        float* m2 = ml + ((size_t)(c * S_LEN + qrow) * H + h) * 2;
        m2[0] = m_[h2];
        m2[1] = lsum;
      }
    } else {
      const float inv = 1.0f / lsum;
      float* orow = out + ((size_t)qrow * H + h) * D;
#pragma unroll
      for (int dc = 0; dc < 4; ++dc) {
        f32x4 o;
        o[0] = acc[h2][dc][0] * inv; o[1] = acc[h2][dc][1] * inv;
        o[2] = acc[h2][dc][2] * inv; o[3] = acc[h2][dc][3] * inv;
        *reinterpret_cast<f32x4*>(orow + dc * 16 + g4 * 4) = o;
      }
    }
  }
}

// one wave per (row, head): merge partials (exp2 domain), normalize, store.
template <int LOG2C>
__global__ __launch_bounds__(256) void combine_kernel(
    const float* __restrict__ po, const float* __restrict__ ml,
    float* __restrict__ out) {
  constexpr int NS = S_LEN >> LOG2C;
  const int lane = threadIdx.x & 63;
  const int widx = (blockIdx.x << 2) + (threadIdx.x >> 6);
  const int h    = widx & 7;
  const int row  = widx >> 3;
  const int cmax = row >> LOG2C;

  float mv[NS];
  float M = -1e30f;
#pragma unroll
  for (int cc = 0; cc < NS; ++cc) {
    mv[cc] = (cc <= cmax) ? ml[((size_t)(cc * S_LEN + row) * H + h) * 2] : -1e30f;
    M = fmaxf(M, mv[cc]);
  }
  float lsum = 0.f, osum = 0.f;
#pragma unroll
  for (int cc = 0; cc < NS; ++cc) {
    if (cc <= cmax) {
      const float w = exp2f(mv[cc] - M);
      lsum += w * ml[((size_t)(cc * S_LEN + row) * H + h) * 2 + 1];
      osum += w * po[((size_t)(cc * S_LEN + row) * H + h) * D + lane];
    }
  }
  out[((size_t)row * H + h) * D + lane] = osum / lsum;
}

extern "C" void kernel_launch(void* const* d_in, const int* in_sizes, int n_in,
                              void* d_out, int out_size, void* d_ws, size_t ws_size,
                              hipStream_t stream) {
  const float* q = (const float*)d_in[0];
  const float* k = (const float*)d_in[1];
  const float* v = (const float*)d_in[2];
  float* out = (float*)d_out;

  const size_t po8 = 8ull * S_LEN * H * D, ml8 = 8ull * S_LEN * H * 2;
  const size_t po4 = 4ull * S_LEN * H * D, ml4 = 4ull * S_LEN * H * 2;

  if (ws_size >= (po8 + ml8) * sizeof(float)) {
    float* po = (float*)d_ws;
    float* ml = po + po8;
    gqa_fwd_kernel<9, true><<<dim3(8 * 8 * NQB), dim3(256), 0, stream>>>(
        q, k, v, out, po, ml);
    combine_kernel<9><<<dim3(S_LEN * H / 4), dim3(256), 0, stream>>>(po, ml, out);
  } else if (ws_size >= (po4 + ml4) * sizeof(float)) {
    float* po = (float*)d_ws;
    float* ml = po + po4;
    gqa_fwd_kernel<10, true><<<dim3(8 * 4 * NQB), dim3(256), 0, stream>>>(
        q, k, v, out, po, ml);
    combine_kernel<10><<<dim3(S_LEN * H / 4), dim3(256), 0, stream>>>(po, ml, out);
  } else {
    gqa_fwd_kernel<12, false><<<dim3(8 * NQB), dim3(256), 0, stream>>>(
        q, k, v, out, nullptr, nullptr);
  }
}